// Round 4
// baseline (1233.237 us; speedup 1.0000x reference)
//
#include <hip/hip_runtime.h>

// Fully-fused 5-layer bidirectional GRU, MFMA for input-gate GEMM.
//
// Mapping: 10 lanes per batch element (2 dirs x 5 hidden units), 6 elems per
// 64-lane wave, 1 wave per block. Recurrent h fp32, all-gathered with
// ds_bpermute each step.
//
// Per layer (1..4): gi[t,e][15 gates] = seq @ wih^T is recurrence-free ->
// computed by 12x mfma_f32_16x16x32_f16 per dir (M=16 (t,e)-rows, N=15
// gates, K=10 channels + bias folded in as constant-1.0 channel k=10;
// activation scales folded into B). D is stored transposed to LDS
// git[dir][gate][p] as f16; the recurrence reads 3 halfs/step and does only
// gh (15 fma) + activations. seq is overwritten in place (gi already
// extracted), so no ping-pong. Layer 4 writes no seq, just final output.
// LDS: seq 192x16 halfs (6144 B) + git 2x16x192 halfs (12288 B) = 18432 B
// -> 8 blocks/CU.

#define NB 262144
#define T 30
#define NP 192          // (t,e) rows padded to 12 MFMA blocks of 16

typedef _Float16 h8 __attribute__((ext_vector_type(8)));
typedef __fp16 p2 __attribute__((ext_vector_type(2)));
typedef float f4 __attribute__((ext_vector_type(4)));

#define SIG_SCALE  (-1.4426950408889634f)   // -log2(e):  sigmoid(x)=1/(1+2^(s*x))
#define TANH_SCALE ( 2.8853900817779268f)   // 2*log2(e): tanh(x)=1-2/(1+2^(s*x))

#define GATHER_H()                                                        \
    do {                                                                  \
        int hb = __float_as_int(hme);                                     \
        h[0] = __int_as_float(__builtin_amdgcn_ds_bpermute(a0, hb));      \
        h[1] = __int_as_float(__builtin_amdgcn_ds_bpermute(a1, hb));      \
        h[2] = __int_as_float(__builtin_amdgcn_ds_bpermute(a2, hb));      \
        h[3] = __int_as_float(__builtin_amdgcn_ds_bpermute(a3, hb));      \
        h[4] = __int_as_float(__builtin_amdgcn_ds_bpermute(a4, hb));      \
    } while (0)

// recurrence for layers 1..4 (gi precomputed in git)
template <bool LAST>
__device__ __forceinline__ void recurH(
    const float* __restrict__ whh, const float* __restrict__ bhh,
    const _Float16* git_d,   // &git[d][0][0], gate stride NP halfs
    _Float16* seqw,          // seq + c (this lane's channel)
    float* outg,
    int e, int d, int j, int a0, int a1, int a2, int a3, int a4)
{
    float wh0[5], wh1[5], wh2[5];
#pragma unroll
    for (int k = 0; k < 5; k++) {
        wh0[k] = SIG_SCALE * whh[j * 5 + k];
        wh1[k] = SIG_SCALE * whh[(j + 5) * 5 + k];
        wh2[k] = TANH_SCALE * whh[(j + 10) * 5 + k];
    }
    const float bnh = TANH_SCALE * bhh[j + 10];

    float h[5] = {0.f, 0.f, 0.f, 0.f, 0.f}, hme = 0.f;
    const int p0 = (d ? (T - 1) * 6 : 0) + e;
    const _Float16* g0 = git_d + j * NP + p0;
    const _Float16* g1 = git_d + (j + 5) * NP + p0;
    const _Float16* g2 = git_d + (j + 10) * NP + p0;
    _Float16* wp = seqw + p0 * 16;
    const int gstep = d ? -6 : 6;
    const int wstep = d ? -96 : 96;
    const int tout = d ? 0 : T - 1;

    for (int t = 0; t < T; t++) {
        float ar = (float)*g0;
        float az = (float)*g1;
        float an = (float)*g2;
        float ah = bnh;
#pragma unroll
        for (int k = 0; k < 5; k++) {
            ar = fmaf(wh0[k], h[k], ar);
            az = fmaf(wh1[k], h[k], az);
            ah = fmaf(wh2[k], h[k], ah);
        }
        float er = __builtin_amdgcn_exp2f(ar);
        float ez = __builtin_amdgcn_exp2f(az);
        float pr = 1.f + er, pz = 1.f + ez;
        float qq = __builtin_amdgcn_rcpf(pr * pz);
        float r = pz * qq;               // 1/(1+er)
        float z = pr * qq;               // 1/(1+ez)
        float u = __builtin_amdgcn_exp2f(fmaf(r, ah, an));
        float n = fmaf(-2.f, __builtin_amdgcn_rcpf(1.f + u), 1.f);
        hme = fmaf(z, hme - n, n);
        if (!LAST) *wp = (_Float16)hme;
        if (LAST) { if (t == tout) *outg = hme; }
        GATHER_H();
        g0 += gstep; g1 += gstep; g2 += gstep;
        if (!LAST) wp += wstep;
    }
}

__global__ void __launch_bounds__(64, 2) gru_all(
    const float* __restrict__ x,
    const float* __restrict__ wih0, const float* __restrict__ whh0,
    const float* __restrict__ bih0, const float* __restrict__ bhh0,
    const float* __restrict__ wihL, const float* __restrict__ whhL,
    const float* __restrict__ bihL, const float* __restrict__ bhhL,
    float* __restrict__ out)
{
    __shared__ __align__(16) _Float16 seq[NP * 16];       // [p][ch0-9,bias,0,0,0,0,0]
    __shared__ __align__(16) _Float16 git[2][16][NP];     // [dir][gate][p]

    const int lane = threadIdx.x;
    const int le = lane < 60 ? lane : 59;   // phantom lanes duplicate lane 59
    const int e = le / 10;
    const int r10 = le - e * 10;
    const int d = r10 / 5;
    const int j = r10 - d * 5;
    const int c = 5 * d + j;
    long b = (long)blockIdx.x * 6 + e;
    if (b >= NB) b = NB - 1;

    const int Lb = (e * 10 + d * 5) * 4;
    const int a0 = Lb, a1 = Lb + 4, a2 = Lb + 8, a3 = Lb + 12, a4 = Lb + 16;

    float* xbuf = (float*)&git[0][0][0];    // overlay: git unused during layer 0

    // init seq pad columns (bias channel = 1.0) and pad rows
    for (int p = lane; p < NP; p += 64) {
        _Float16* row = seq + p * 16;
        if (p >= 6 * T) {
#pragma unroll
            for (int k = 0; k < 10; k++) row[k] = (_Float16)0.f;
        }
        row[10] = (_Float16)1.0f;
#pragma unroll
        for (int k = 11; k < 16; k++) row[k] = (_Float16)0.f;
    }

    // stage x into xbuf[t][e]
    for (int f = lane; f < 6 * T; f += 64) {
        int ee = f / T, tt = f - ee * T;
        long bb = (long)blockIdx.x * 6 + ee;
        if (bb >= NB) bb = NB - 1;
        xbuf[tt * 6 + ee] = x[bb * T + tt];
    }
    __syncthreads();

    // ---- layer 0 (input dim 1, scalar gi) ----
    {
        const float* wih = wih0 + d * 15;
        const float* whh = whh0 + d * 75;
        const float* bih = bih0 + d * 15;
        const float* bhh = bhh0 + d * 15;
        const float wr = SIG_SCALE * wih[j];
        const float wz = SIG_SCALE * wih[j + 5];
        const float wn = TANH_SCALE * wih[j + 10];
        float wh0[5], wh1[5], wh2[5];
#pragma unroll
        for (int k = 0; k < 5; k++) {
            wh0[k] = SIG_SCALE * whh[j * 5 + k];
            wh1[k] = SIG_SCALE * whh[(j + 5) * 5 + k];
            wh2[k] = TANH_SCALE * whh[(j + 10) * 5 + k];
        }
        const float br  = SIG_SCALE * (bih[j] + bhh[j]);
        const float bz  = SIG_SCALE * (bih[j + 5] + bhh[j + 5]);
        const float bni = TANH_SCALE * bih[j + 10];
        const float bnh = TANH_SCALE * bhh[j + 10];

        float h[5] = {0.f, 0.f, 0.f, 0.f, 0.f}, hme = 0.f;
        const float* xp = xbuf + (d ? (T - 1) * 6 : 0) + e;
        _Float16* wp = seq + ((d ? (T - 1) * 6 : 0) + e) * 16 + c;
        const int xstep = d ? -6 : 6;
        const int wstep = d ? -96 : 96;

        for (int t = 0; t < T; t++) {
            float xv = *xp;
            float ar = fmaf(wr, xv, br);
            float az = fmaf(wz, xv, bz);
            float an = fmaf(wn, xv, bni);
            float ah = bnh;
#pragma unroll
            for (int k = 0; k < 5; k++) {
                ar = fmaf(wh0[k], h[k], ar);
                az = fmaf(wh1[k], h[k], az);
                ah = fmaf(wh2[k], h[k], ah);
            }
            float er = __builtin_amdgcn_exp2f(ar);
            float ez = __builtin_amdgcn_exp2f(az);
            float pr = 1.f + er, pz = 1.f + ez;
            float qq = __builtin_amdgcn_rcpf(pr * pz);
            float r = pz * qq, z = pr * qq;
            float u = __builtin_amdgcn_exp2f(fmaf(r, ah, an));
            float n = fmaf(-2.f, __builtin_amdgcn_rcpf(1.f + u), 1.f);
            hme = fmaf(z, hme - n, n);
            *wp = (_Float16)hme;
            GATHER_H();
            xp += xstep;
            wp += wstep;
        }
    }
    __syncthreads();

    // ---- layers 1..4: MFMA gi, then recurrence ----
    const int g = lane & 15, q = lane >> 4;
    for (int l = 1; l < 5; l++) {
        // gi GEMM: one pass per direction
        for (int d2 = 0; d2 < 2; d2++) {
            const int od = (l - 1) * 2 + d2;
            h8 bf = {0, 0, 0, 0, 0, 0, 0, 0};
            if (g < 15) {
                const float sc = (g < 10) ? SIG_SCALE : TANH_SCALE;
                const float* wr = wihL + od * 150 + g * 10;
                if (q == 0) {
#pragma unroll
                    for (int k = 0; k < 8; k++) bf[k] = (_Float16)(sc * wr[k]);
                } else if (q == 1) {
                    bf[0] = (_Float16)(sc * wr[8]);
                    bf[1] = (_Float16)(sc * wr[9]);
                    float bias = bihL[od * 15 + g] + (g < 10 ? bhhL[od * 15 + g] : 0.f);
                    bf[2] = (_Float16)(sc * bias);   // k=10 = constant-1.0 channel
                }
            }
#pragma unroll
            for (int blk = 0; blk < 12; blk++) {
                h8 af = {0, 0, 0, 0, 0, 0, 0, 0};
                if (q < 2) af = *(const h8*)(seq + (blk * 16 + g) * 16 + q * 8);
                f4 dd = __builtin_amdgcn_mfma_f32_16x16x32_f16(af, bf, (f4){0.f, 0.f, 0.f, 0.f}, 0, 0, 0);
                p2* wp2 = (p2*)&git[d2][g][blk * 16 + q * 4];
                wp2[0] = __builtin_amdgcn_cvt_pkrtz(dd[0], dd[1]);
                wp2[1] = __builtin_amdgcn_cvt_pkrtz(dd[2], dd[3]);
            }
        }
        __syncthreads();

        const int od = (l - 1) * 2 + d;
        if (l < 4) {
            recurH<false>(whhL + od * 75, bhhL + od * 15,
                          &git[d][0][0], seq + c, nullptr,
                          e, d, j, a0, a1, a2, a3, a4);
        } else {
            recurH<true>(whhL + od * 75, bhhL + od * 15,
                         &git[d][0][0], seq + c, out + b * 10 + c,
                         e, d, j, a0, a1, a2, a3, a4);
        }
        __syncthreads();
    }
}

extern "C" void kernel_launch(void* const* d_in, const int* in_sizes, int n_in,
                              void* d_out, int out_size, void* d_ws, size_t ws_size,
                              hipStream_t stream) {
    const float* x    = (const float*)d_in[0];
    const float* wih0 = (const float*)d_in[1];
    const float* whh0 = (const float*)d_in[2];
    const float* bih0 = (const float*)d_in[3];
    const float* bhh0 = (const float*)d_in[4];
    const float* wihL = (const float*)d_in[5];
    const float* whhL = (const float*)d_in[6];
    const float* bihL = (const float*)d_in[7];
    const float* bhhL = (const float*)d_in[8];
    float* out = (float*)d_out;

    const int blocks = (NB + 5) / 6;   // 6 batch elements per 64-lane wave
    gru_all<<<blocks, 64, 0, stream>>>(x, wih0, whh0, bih0, bhh0,
                                       wihL, whhL, bihL, bhhL, out);
}

// Round 6
// 744.880 us; speedup vs baseline: 1.6556x; 1.6556x over previous
//
#include <hip/hip_runtime.h>

// Fully-fused 5-layer bidirectional GRU — thread-per-(element,direction).
//
// Each lane owns one (batch element, direction): full h[5] in registers, no
// cross-lane traffic at all. gi = 75 fdot2 (f16 pairs from LDS seq), gh = 45
// fdot2 (h packed to f16), activations via exp2 with -log2e / 2*log2e folded
// into weights+biases. 30 elems per 64-lane wave (lanes 60-63 duplicate),
// 1 wave/block. Seq ping-pong in LDS as f16, row stride 302 halfs; per-
// instruction accesses are <=2-way bank conflicted (free). Writes are five
// scalar half stores: the bwd lane's channel base e*10+5 is odd, so 4-byte
// vector stores would be misaligned (R5 bug #2); R5 bug #1 was both dirs
// writing channels 0-4 (missing +5*d), leaving 5-9 uninitialized -> NaN.
// Weights staged to LDS pre-scaled f16 once, loaded to VGPRs per layer.
// LDS = 36240 (seq) + 2400 (Wih) + 1800 (Whh) = 40440 B -> 4 blocks/CU.
// Layer 4 writes no seq, just the final output.

#define NB 262144
#define T 30
#define EPW 30              // elements per wave
#define RROW 302            // seq row stride in halfs (30*10 + 2 pad)
#define NBLK ((NB + EPW - 1) / EPW)

typedef __fp16 p2 __attribute__((ext_vector_type(2)));

#define SIG_SCALE  (-1.4426950408889634f)   // -log2(e):  sigmoid(x)=1/(1+2^(s*x))
#define TANH_SCALE ( 2.8853900817779268f)   // 2*log2(e): tanh(x)=1-2/(1+2^(s*x))

__device__ __forceinline__ float fdot2f(p2 a, p2 b, float c) {
    return __builtin_amdgcn_fdot2(a, b, c, false);
}

// hidden layers 1..4: input = 10 f16 channels from LDS seq
template <bool WRITE, bool FINAL>
__device__ __forceinline__ void layer_h(
    const _Float16* __restrict__ Win,   // [15][10] pre-scaled f16
    const _Float16* __restrict__ Whn,   // [15][6]  pre-scaled f16 (6th = 0)
    const float* __restrict__ bihg, const float* __restrict__ bhhg,  // global, 15 each
    const _Float16* sin_, _Float16* sout, float* outg,
    int e, int d)
{
    p2 wi[15][5], wh[15][3];
#pragma unroll
    for (int g = 0; g < 15; g++) {
#pragma unroll
        for (int k = 0; k < 5; k++) wi[g][k] = *(const p2*)(Win + g * 10 + 2 * k);
#pragma unroll
        for (int k = 0; k < 3; k++) wh[g][k] = *(const p2*)(Whn + g * 6 + 2 * k);
    }
    float bia[15], bnh[5];
#pragma unroll
    for (int g = 0; g < 15; g++)
        bia[g] = (g < 10) ? SIG_SCALE * (bihg[g] + bhhg[g]) : TANH_SCALE * bihg[g];
#pragma unroll
    for (int u = 0; u < 5; u++) bnh[u] = TANH_SCALE * bhhg[10 + u];

    float hf[5] = {0.f, 0.f, 0.f, 0.f, 0.f};
    p2 h01 = p2{0, 0}, h23 = p2{0, 0}, h45 = p2{0, 0};

    const int rstep = d ? -RROW : RROW;
    const _Float16* rp = sin_ + (d ? (T - 1) * RROW : 0) + e * 10;
    _Float16* wp = sout + (d ? (T - 1) * RROW : 0) + e * 10 + 5 * d;
    const int slast = FINAL ? (d ? 0 : T - 1) : -1;

#pragma unroll 1
    for (int s = 0; s < T; s++) {
        p2 x0 = *(const p2*)(rp + 0);
        p2 x1 = *(const p2*)(rp + 2);
        p2 x2 = *(const p2*)(rp + 4);
        p2 x3 = *(const p2*)(rp + 6);
        p2 x4 = *(const p2*)(rp + 8);
        float acc[15];
#pragma unroll
        for (int g = 0; g < 15; g++) {
            float a = bia[g];
            a = fdot2f(wi[g][0], x0, a);
            a = fdot2f(wi[g][1], x1, a);
            a = fdot2f(wi[g][2], x2, a);
            a = fdot2f(wi[g][3], x3, a);
            a = fdot2f(wi[g][4], x4, a);
            acc[g] = a;
        }
#pragma unroll
        for (int u = 0; u < 5; u++) {
            float ar = acc[u], az = acc[u + 5], ah = bnh[u];
            ar = fdot2f(wh[u][0], h01, ar);
            ar = fdot2f(wh[u][1], h23, ar);
            ar = fdot2f(wh[u][2], h45, ar);
            az = fdot2f(wh[u + 5][0], h01, az);
            az = fdot2f(wh[u + 5][1], h23, az);
            az = fdot2f(wh[u + 5][2], h45, az);
            ah = fdot2f(wh[u + 10][0], h01, ah);
            ah = fdot2f(wh[u + 10][1], h23, ah);
            ah = fdot2f(wh[u + 10][2], h45, ah);
            float er = __builtin_amdgcn_exp2f(ar);
            float ez = __builtin_amdgcn_exp2f(az);
            float pr = 1.f + er, pz = 1.f + ez;
            float qq = __builtin_amdgcn_rcpf(pr * pz);
            float r = pz * qq, z = pr * qq;
            float uu = __builtin_amdgcn_exp2f(fmaf(r, ah, acc[u + 10]));
            float n = fmaf(-2.f, __builtin_amdgcn_rcpf(1.f + uu), 1.f);
            hf[u] = fmaf(z, hf[u] - n, n);
        }
        h01 = __builtin_amdgcn_cvt_pkrtz(hf[0], hf[1]);
        h23 = __builtin_amdgcn_cvt_pkrtz(hf[2], hf[3]);
        h45 = __builtin_amdgcn_cvt_pkrtz(hf[4], 0.f);
        if (WRITE) {
            wp[0] = (_Float16)h01.x;
            wp[1] = (_Float16)h01.y;
            wp[2] = (_Float16)h23.x;
            wp[3] = (_Float16)h23.y;
            wp[4] = (_Float16)h45.x;
            wp += rstep;
        }
        if (FINAL && s == slast) {
#pragma unroll
            for (int u = 0; u < 5; u++) outg[u] = hf[u];
        }
        rp += rstep;
    }
}

__global__ void __launch_bounds__(64, 1) gru_all(
    const float* __restrict__ x,
    const float* __restrict__ wih0, const float* __restrict__ whh0,
    const float* __restrict__ bih0, const float* __restrict__ bhh0,
    const float* __restrict__ wihL, const float* __restrict__ whhL,
    const float* __restrict__ bihL, const float* __restrict__ bhhL,
    float* __restrict__ out)
{
    __shared__ __align__(16) _Float16 seq[2][T * RROW];   // 36240 B
    __shared__ __align__(16) _Float16 Wih[8][15][10];     //  2400 B
    __shared__ __align__(16) _Float16 Whh[10][15][6];     //  1800 B (0,1 = layer0)

    const int lane = threadIdx.x;
    int e = lane >> 1; if (e >= EPW) e = EPW - 1;   // lanes 60-63 duplicate
    const int d = lane & 1;
    long b = (long)blockIdx.x * EPW + e;
    if (b >= NB) b = NB - 1;

    // ---- stage weights (pre-scaled f16) ----
    for (int task = lane; task < 150; task += 64) {       // Whh: 10 entries
        int en = task / 15, g = task % 15;
        float sc = (g < 10) ? SIG_SCALE : TANH_SCALE;
        const float* src = (en < 2) ? (whh0 + en * 75 + g * 5)
                                    : (whhL + (en - 2) * 75 + g * 5);
#pragma unroll
        for (int k = 0; k < 5; k++) Whh[en][g][k] = (_Float16)(sc * src[k]);
        Whh[en][g][5] = (_Float16)0.f;
    }
    for (int task = lane; task < 120; task += 64) {       // Wih: 8 entries
        int od = task / 15, g = task % 15;
        float sc = (g < 10) ? SIG_SCALE : TANH_SCALE;
        const float* src = wihL + od * 150 + g * 10;
#pragma unroll
        for (int k = 0; k < 10; k++) Wih[od][g][k] = (_Float16)(sc * src[k]);
    }
    // ---- stage x as f32 [t][e], overlaid on seq[1] ----
    float* xb = (float*)&seq[1][0];                       // 3600 B < 18120
    for (int i = lane; i < EPW * T; i += 64) {
        int ee = i / T, tt = i % T;
        long bb = (long)blockIdx.x * EPW + ee;
        if (bb >= NB) bb = NB - 1;
        xb[tt * EPW + ee] = x[bb * T + tt];
    }
    __syncthreads();

    // ---- layer 0 (input dim 1): reads xb (seq[1] overlay), writes seq[0] ----
    {
        p2 wh[15][3];
        const _Float16* Whn = &Whh[d][0][0];
#pragma unroll
        for (int g = 0; g < 15; g++)
#pragma unroll
            for (int k = 0; k < 3; k++) wh[g][k] = *(const p2*)(Whn + g * 6 + 2 * k);
        const float* bihg = bih0 + d * 15;
        const float* bhhg = bhh0 + d * 15;
        const float* wig = wih0 + d * 15;
        float wi0[15], bia[15], bnh[5];
#pragma unroll
        for (int g = 0; g < 15; g++) {
            float sc = (g < 10) ? SIG_SCALE : TANH_SCALE;
            wi0[g] = sc * wig[g];
            bia[g] = (g < 10) ? SIG_SCALE * (bihg[g] + bhhg[g]) : TANH_SCALE * bihg[g];
        }
#pragma unroll
        for (int u = 0; u < 5; u++) bnh[u] = TANH_SCALE * bhhg[10 + u];

        float hf[5] = {0.f, 0.f, 0.f, 0.f, 0.f};
        p2 h01 = p2{0, 0}, h23 = p2{0, 0}, h45 = p2{0, 0};
        const float* xp = xb + (d ? (T - 1) * EPW : 0) + e;
        _Float16* wp = &seq[0][0] + (d ? (T - 1) * RROW : 0) + e * 10 + 5 * d;
        const int xstep = d ? -EPW : EPW;
        const int rstep = d ? -RROW : RROW;

#pragma unroll 1
        for (int s = 0; s < T; s++) {
            float xt = *xp;
            float acc[15];
#pragma unroll
            for (int g = 0; g < 15; g++) acc[g] = fmaf(wi0[g], xt, bia[g]);
#pragma unroll
            for (int u = 0; u < 5; u++) {
                float ar = acc[u], az = acc[u + 5], ah = bnh[u];
                ar = fdot2f(wh[u][0], h01, ar);
                ar = fdot2f(wh[u][1], h23, ar);
                ar = fdot2f(wh[u][2], h45, ar);
                az = fdot2f(wh[u + 5][0], h01, az);
                az = fdot2f(wh[u + 5][1], h23, az);
                az = fdot2f(wh[u + 5][2], h45, az);
                ah = fdot2f(wh[u + 10][0], h01, ah);
                ah = fdot2f(wh[u + 10][1], h23, ah);
                ah = fdot2f(wh[u + 10][2], h45, ah);
                float er = __builtin_amdgcn_exp2f(ar);
                float ez = __builtin_amdgcn_exp2f(az);
                float pr = 1.f + er, pz = 1.f + ez;
                float qq = __builtin_amdgcn_rcpf(pr * pz);
                float r = pz * qq, z = pr * qq;
                float uu = __builtin_amdgcn_exp2f(fmaf(r, ah, acc[u + 10]));
                float n = fmaf(-2.f, __builtin_amdgcn_rcpf(1.f + uu), 1.f);
                hf[u] = fmaf(z, hf[u] - n, n);
            }
            h01 = __builtin_amdgcn_cvt_pkrtz(hf[0], hf[1]);
            h23 = __builtin_amdgcn_cvt_pkrtz(hf[2], hf[3]);
            h45 = __builtin_amdgcn_cvt_pkrtz(hf[4], 0.f);
            wp[0] = (_Float16)h01.x;
            wp[1] = (_Float16)h01.y;
            wp[2] = (_Float16)h23.x;
            wp[3] = (_Float16)h23.y;
            wp[4] = (_Float16)h45.x;
            wp += rstep;
            xp += xstep;
        }
    }
    __syncthreads();

    // ---- layers 1..3: ping-pong; layer 4: final ----
    // seq[0] -> seq[1] -> seq[0] -> seq[1] -> out
#pragma unroll 1
    for (int l = 1; l < 4; l++) {
        const int od = (l - 1) * 2 + d;
        const int src = (l & 1) ? 0 : 1;
        layer_h<true, false>(&Wih[od][0][0], &Whh[od + 2][0][0],
                             bihL + od * 15, bhhL + od * 15,
                             &seq[src][0], &seq[src ^ 1][0], nullptr, e, d);
        __syncthreads();
    }
    {
        const int od = 3 * 2 + d;
        layer_h<false, true>(&Wih[od][0][0], &Whh[od + 2][0][0],
                             bihL + od * 15, bhhL + od * 15,
                             &seq[1][0], &seq[0][0], out + b * 10 + d * 5, e, d);
    }
}

extern "C" void kernel_launch(void* const* d_in, const int* in_sizes, int n_in,
                              void* d_out, int out_size, void* d_ws, size_t ws_size,
                              hipStream_t stream) {
    const float* x    = (const float*)d_in[0];
    const float* wih0 = (const float*)d_in[1];
    const float* whh0 = (const float*)d_in[2];
    const float* bih0 = (const float*)d_in[3];
    const float* bhh0 = (const float*)d_in[4];
    const float* wihL = (const float*)d_in[5];
    const float* whhL = (const float*)d_in[6];
    const float* bihL = (const float*)d_in[7];
    const float* bhhL = (const float*)d_in[8];
    float* out = (float*)d_out;

    gru_all<<<NBLK, 64, 0, stream>>>(x, wih0, whh0, bih0, bhh0,
                                     wihL, whhL, bihL, bhhL, out);
}

// Round 7
// 715.484 us; speedup vs baseline: 1.7236x; 1.0411x over previous
//
#include <hip/hip_runtime.h>

// Fully-fused 5-layer bidirectional GRU — thread-per-(element,direction),
// software-pipelined LDS reads.
//
// Each lane owns one (batch element, direction): full h[5] in registers, no
// cross-lane traffic. gi = 75 fdot2 (f16 pairs from LDS seq), gh = 45 fdot2
// (h packed to f16), activations via exp2 with -log2e / 2*log2e folded into
// weights+biases. 30 elems per 64-lane wave, 1 wave/block.
//
// R6 measured VALUBusy 70% @ 1 wave/SIMD: the 5 ds_read at each step's top
// feed gi immediately -> ~120 cyc LDS latency exposed every step. R7:
// prefetch x rows 1-2 steps ahead (rotating XA/XB, unroll x2, epilogue keeps
// all loads in [0,T) so the bwd negative-stride pointer never underflows).
// gi of step s+1 is independent of the recurrence, so the scheduler can
// overlap it with step s's activation chain.
//
// LDS = 36240 (seq ping-pong) + 2400 (Wih) + 1800 (Whh) = 40440 B
// -> 4 blocks/CU (structural cap: ~1.2 KB LDS per elem). Layer 4 writes no
// seq, just the final output.

#define NB 262144
#define T 30
#define EPW 30              // elements per wave
#define RROW 302            // seq row stride in halfs (30*10 + 2 pad)
#define NBLK ((NB + EPW - 1) / EPW)

typedef __fp16 p2 __attribute__((ext_vector_type(2)));

#define SIG_SCALE  (-1.4426950408889634f)   // -log2(e):  sigmoid(x)=1/(1+2^(s*x))
#define TANH_SCALE ( 2.8853900817779268f)   // 2*log2(e): tanh(x)=1-2/(1+2^(s*x))

__device__ __forceinline__ float fdot2f(p2 a, p2 b, float c) {
    return __builtin_amdgcn_fdot2(a, b, c, false);
}

// hidden layers 1..4: input = 10 f16 channels from LDS seq
template <bool WRITE, bool FINAL>
__device__ __forceinline__ void layer_h(
    const _Float16* __restrict__ Win,   // [15][10] pre-scaled f16
    const _Float16* __restrict__ Whn,   // [15][6]  pre-scaled f16 (6th = 0)
    const float* __restrict__ bihg, const float* __restrict__ bhhg,  // global, 15 each
    const _Float16* sin_, _Float16* sout, float* outg,
    int e, int d)
{
    p2 wi[15][5], wh[15][3];
#pragma unroll
    for (int g = 0; g < 15; g++) {
#pragma unroll
        for (int k = 0; k < 5; k++) wi[g][k] = *(const p2*)(Win + g * 10 + 2 * k);
#pragma unroll
        for (int k = 0; k < 3; k++) wh[g][k] = *(const p2*)(Whn + g * 6 + 2 * k);
    }
    float bia[15], bnh[5];
#pragma unroll
    for (int g = 0; g < 15; g++)
        bia[g] = (g < 10) ? SIG_SCALE * (bihg[g] + bhhg[g]) : TANH_SCALE * bihg[g];
#pragma unroll
    for (int u = 0; u < 5; u++) bnh[u] = TANH_SCALE * bhhg[10 + u];

    float hf[5] = {0.f, 0.f, 0.f, 0.f, 0.f};
    p2 h01 = p2{0, 0}, h23 = p2{0, 0}, h45 = p2{0, 0};

    const int rstep = d ? -RROW : RROW;
    const _Float16* rp = sin_ + (d ? (T - 1) * RROW : 0) + e * 10;
    _Float16* wp = sout + (d ? (T - 1) * RROW : 0) + e * 10 + 5 * d;
    const int slast = d ? 0 : T - 1;

    p2 XA[5], XB[5];

#define LOADX(dst)                                                        \
    do {                                                                  \
        dst[0] = *(const p2*)(rp + 0);                                    \
        dst[1] = *(const p2*)(rp + 2);                                    \
        dst[2] = *(const p2*)(rp + 4);                                    \
        dst[3] = *(const p2*)(rp + 6);                                    \
        dst[4] = *(const p2*)(rp + 8);                                    \
        rp += rstep;                                                      \
    } while (0)

    auto compute = [&](const p2* xv, int s) {
        float acc[15];
#pragma unroll
        for (int g = 0; g < 15; g++) {
            float a = bia[g];
            a = fdot2f(wi[g][0], xv[0], a);
            a = fdot2f(wi[g][1], xv[1], a);
            a = fdot2f(wi[g][2], xv[2], a);
            a = fdot2f(wi[g][3], xv[3], a);
            a = fdot2f(wi[g][4], xv[4], a);
            acc[g] = a;
        }
#pragma unroll
        for (int u = 0; u < 5; u++) {
            float ar = acc[u], az = acc[u + 5], ah = bnh[u];
            ar = fdot2f(wh[u][0], h01, ar);
            ar = fdot2f(wh[u][1], h23, ar);
            ar = fdot2f(wh[u][2], h45, ar);
            az = fdot2f(wh[u + 5][0], h01, az);
            az = fdot2f(wh[u + 5][1], h23, az);
            az = fdot2f(wh[u + 5][2], h45, az);
            ah = fdot2f(wh[u + 10][0], h01, ah);
            ah = fdot2f(wh[u + 10][1], h23, ah);
            ah = fdot2f(wh[u + 10][2], h45, ah);
            float er = __builtin_amdgcn_exp2f(ar);
            float ez = __builtin_amdgcn_exp2f(az);
            float pr = 1.f + er, pz = 1.f + ez;
            float qq = __builtin_amdgcn_rcpf(pr * pz);
            float r = pz * qq, z = pr * qq;
            float uu = __builtin_amdgcn_exp2f(fmaf(r, ah, acc[u + 10]));
            float n = fmaf(-2.f, __builtin_amdgcn_rcpf(1.f + uu), 1.f);
            hf[u] = fmaf(z, hf[u] - n, n);
        }
        h01 = __builtin_amdgcn_cvt_pkrtz(hf[0], hf[1]);
        h23 = __builtin_amdgcn_cvt_pkrtz(hf[2], hf[3]);
        h45 = __builtin_amdgcn_cvt_pkrtz(hf[4], 0.f);
        if (WRITE) {
            wp[0] = (_Float16)h01.x;
            wp[1] = (_Float16)h01.y;
            wp[2] = (_Float16)h23.x;
            wp[3] = (_Float16)h23.y;
            wp[4] = (_Float16)h45.x;
            wp += rstep;
        }
        if (FINAL && s == slast) {
#pragma unroll
            for (int u = 0; u < 5; u++) outg[u] = hf[u];
        }
    };

    LOADX(XA);                       // step 0
#pragma unroll 1
    for (int it = 0; it < 14; it++) {
        LOADX(XB);                   // step 2it+1
        compute(XA, 2 * it);
        LOADX(XA);                   // step 2it+2
        compute(XB, 2 * it + 1);
    }
    LOADX(XB);                       // step 29
    compute(XA, 28);
    compute(XB, 29);
#undef LOADX
}

__global__ void __launch_bounds__(64, 1) gru_all(
    const float* __restrict__ x,
    const float* __restrict__ wih0, const float* __restrict__ whh0,
    const float* __restrict__ bih0, const float* __restrict__ bhh0,
    const float* __restrict__ wihL, const float* __restrict__ whhL,
    const float* __restrict__ bihL, const float* __restrict__ bhhL,
    float* __restrict__ out)
{
    __shared__ __align__(16) _Float16 seq[2][T * RROW];   // 36240 B
    __shared__ __align__(16) _Float16 Wih[8][15][10];     //  2400 B
    __shared__ __align__(16) _Float16 Whh[10][15][6];     //  1800 B (0,1 = layer0)

    const int lane = threadIdx.x;
    int e = lane >> 1; if (e >= EPW) e = EPW - 1;   // lanes 60-63 duplicate
    const int d = lane & 1;
    long b = (long)blockIdx.x * EPW + e;
    if (b >= NB) b = NB - 1;

    // ---- stage weights (pre-scaled f16) ----
    for (int task = lane; task < 150; task += 64) {       // Whh: 10 entries
        int en = task / 15, g = task % 15;
        float sc = (g < 10) ? SIG_SCALE : TANH_SCALE;
        const float* src = (en < 2) ? (whh0 + en * 75 + g * 5)
                                    : (whhL + (en - 2) * 75 + g * 5);
#pragma unroll
        for (int k = 0; k < 5; k++) Whh[en][g][k] = (_Float16)(sc * src[k]);
        Whh[en][g][5] = (_Float16)0.f;
    }
    for (int task = lane; task < 120; task += 64) {       // Wih: 8 entries
        int od = task / 15, g = task % 15;
        float sc = (g < 10) ? SIG_SCALE : TANH_SCALE;
        const float* src = wihL + od * 150 + g * 10;
#pragma unroll
        for (int k = 0; k < 10; k++) Wih[od][g][k] = (_Float16)(sc * src[k]);
    }
    // ---- stage x as f32 [t][e], overlaid on seq[1] ----
    float* xb = (float*)&seq[1][0];                       // 3600 B < 18120
    for (int i = lane; i < EPW * T; i += 64) {
        int ee = i / T, tt = i % T;
        long bb = (long)blockIdx.x * EPW + ee;
        if (bb >= NB) bb = NB - 1;
        xb[tt * EPW + ee] = x[bb * T + tt];
    }
    __syncthreads();

    // ---- layer 0 (input dim 1): reads xb (seq[1] overlay), writes seq[0] ----
    {
        p2 wh[15][3];
        const _Float16* Whn = &Whh[d][0][0];
#pragma unroll
        for (int g = 0; g < 15; g++)
#pragma unroll
            for (int k = 0; k < 3; k++) wh[g][k] = *(const p2*)(Whn + g * 6 + 2 * k);
        const float* bihg = bih0 + d * 15;
        const float* bhhg = bhh0 + d * 15;
        const float* wig = wih0 + d * 15;
        float wi0[15], bia[15], bnh[5];
#pragma unroll
        for (int g = 0; g < 15; g++) {
            float sc = (g < 10) ? SIG_SCALE : TANH_SCALE;
            wi0[g] = sc * wig[g];
            bia[g] = (g < 10) ? SIG_SCALE * (bihg[g] + bhhg[g]) : TANH_SCALE * bihg[g];
        }
#pragma unroll
        for (int u = 0; u < 5; u++) bnh[u] = TANH_SCALE * bhhg[10 + u];

        float hf[5] = {0.f, 0.f, 0.f, 0.f, 0.f};
        p2 h01 = p2{0, 0}, h23 = p2{0, 0}, h45 = p2{0, 0};
        const float* xp = xb + (d ? (T - 1) * EPW : 0) + e;
        _Float16* wp = &seq[0][0] + (d ? (T - 1) * RROW : 0) + e * 10 + 5 * d;
        const int xstep = d ? -EPW : EPW;
        const int rstep = d ? -RROW : RROW;

        auto compute0 = [&](float xt) {
            float acc[15];
#pragma unroll
            for (int g = 0; g < 15; g++) acc[g] = fmaf(wi0[g], xt, bia[g]);
#pragma unroll
            for (int u = 0; u < 5; u++) {
                float ar = acc[u], az = acc[u + 5], ah = bnh[u];
                ar = fdot2f(wh[u][0], h01, ar);
                ar = fdot2f(wh[u][1], h23, ar);
                ar = fdot2f(wh[u][2], h45, ar);
                az = fdot2f(wh[u + 5][0], h01, az);
                az = fdot2f(wh[u + 5][1], h23, az);
                az = fdot2f(wh[u + 5][2], h45, az);
                ah = fdot2f(wh[u + 10][0], h01, ah);
                ah = fdot2f(wh[u + 10][1], h23, ah);
                ah = fdot2f(wh[u + 10][2], h45, ah);
                float er = __builtin_amdgcn_exp2f(ar);
                float ez = __builtin_amdgcn_exp2f(az);
                float pr = 1.f + er, pz = 1.f + ez;
                float qq = __builtin_amdgcn_rcpf(pr * pz);
                float r = pz * qq, z = pr * qq;
                float uu = __builtin_amdgcn_exp2f(fmaf(r, ah, acc[u + 10]));
                float n = fmaf(-2.f, __builtin_amdgcn_rcpf(1.f + uu), 1.f);
                hf[u] = fmaf(z, hf[u] - n, n);
            }
            h01 = __builtin_amdgcn_cvt_pkrtz(hf[0], hf[1]);
            h23 = __builtin_amdgcn_cvt_pkrtz(hf[2], hf[3]);
            h45 = __builtin_amdgcn_cvt_pkrtz(hf[4], 0.f);
            wp[0] = (_Float16)h01.x;
            wp[1] = (_Float16)h01.y;
            wp[2] = (_Float16)h23.x;
            wp[3] = (_Float16)h23.y;
            wp[4] = (_Float16)h45.x;
            wp += rstep;
        };

        float xA, xB;
        xA = *xp; xp += xstep;                 // step 0
#pragma unroll 1
        for (int it = 0; it < 14; it++) {
            xB = *xp; xp += xstep;             // step 2it+1
            compute0(xA);
            xA = *xp; xp += xstep;             // step 2it+2
            compute0(xB);
        }
        xB = *xp;                              // step 29
        compute0(xA);
        compute0(xB);
    }
    __syncthreads();

    // ---- layers 1..3: ping-pong; layer 4: final ----
    // seq[0] -> seq[1] -> seq[0] -> seq[1] -> out
#pragma unroll 1
    for (int l = 1; l < 4; l++) {
        const int od = (l - 1) * 2 + d;
        const int src = (l & 1) ? 0 : 1;
        layer_h<true, false>(&Wih[od][0][0], &Whh[od + 2][0][0],
                             bihL + od * 15, bhhL + od * 15,
                             &seq[src][0], &seq[src ^ 1][0], nullptr, e, d);
        __syncthreads();
    }
    {
        const int od = 3 * 2 + d;
        layer_h<false, true>(&Wih[od][0][0], &Whh[od + 2][0][0],
                             bihL + od * 15, bhhL + od * 15,
                             &seq[1][0], &seq[0][0], out + b * 10 + d * 5, e, d);
    }
}

extern "C" void kernel_launch(void* const* d_in, const int* in_sizes, int n_in,
                              void* d_out, int out_size, void* d_ws, size_t ws_size,
                              hipStream_t stream) {
    const float* x    = (const float*)d_in[0];
    const float* wih0 = (const float*)d_in[1];
    const float* whh0 = (const float*)d_in[2];
    const float* bih0 = (const float*)d_in[3];
    const float* bhh0 = (const float*)d_in[4];
    const float* wihL = (const float*)d_in[5];
    const float* whhL = (const float*)d_in[6];
    const float* bihL = (const float*)d_in[7];
    const float* bhhL = (const float*)d_in[8];
    float* out = (float*)d_out;

    gru_all<<<NBLK, 64, 0, stream>>>(x, wih0, whh0, bih0, bhh0,
                                     wihL, whhL, bihL, bhhL, out);
}